// Round 2
// baseline (14952.533 us; speedup 1.0000x reference)
//
#include <hip/hip_runtime.h>
#include <stdint.h>

#define H 256
#define BB 64
#define TT 2048
#define G4 1024
#define LDX 264   // padded LDS row stride (elems): 528 B, 16B-aligned, balanced banks

typedef __attribute__((ext_vector_type(8))) short short8;
typedef __attribute__((ext_vector_type(4))) float float4_;
typedef unsigned long long ull;
typedef unsigned short ushort_t;
typedef unsigned int uint_t;
typedef __attribute__((ext_vector_type(4))) uint_t uint4_;

static __device__ __forceinline__ float bfhi2f(ushort_t u) {
    union { unsigned int i; float f; } v; v.i = ((unsigned int)u) << 16; return v.f;
}
static __device__ __forceinline__ ushort_t f2bf(float x) {
    union { float f; unsigned int i; } v; v.f = x;
    unsigned int u = v.i;
    return (ushort_t)((u + 0x7FFFu + ((u >> 16) & 1u)) >> 16);
}
static __device__ __forceinline__ void split2(float x, ushort_t& hi, ushort_t& lo) {
    hi = f2bf(x);
    lo = f2bf(x - bfhi2f(hi));
}
static __device__ __forceinline__ float sigm(float x) { return 1.0f / (1.0f + __expf(-x)); }
static __device__ __forceinline__ float tanh_(float x) { return 2.0f / (1.0f + __expf(-2.0f * x)) - 1.0f; }

// ---- split fp32 weights into transposed bf16 hi/lo planes: planes[mat][plane][g][k] ----
__global__ __launch_bounds__(256) void split_w(const float* __restrict__ Wx,
                                               const float* __restrict__ Wh,
                                               ushort_t* __restrict__ planes) {
    const int g = blockIdx.x & 1023;
    const int mat = blockIdx.x >> 10;
    const int k = threadIdx.x;
    const float* src = mat ? Wh : Wx;
    float v = src[(size_t)k * G4 + g];
    ushort_t hi, lo; split2(v, hi, lo);
    ushort_t* ph = planes + (size_t)mat * 2 * G4 * 256;
    ph[g * 256 + k] = hi;
    ph[(size_t)G4 * 256 + g * 256 + k] = lo;
}

// ---- fused LSTM scan, split-bf16 (fp32-grade) arithmetic ----
// 256 blocks launched; 64 become workers via XCD-claimed placement so each group's
// 16 blocks share one XCD. h exchange: single-writer tagged fp32 words (low 7 mantissa
// bits = step tag, discarded by the bf16 split anyway).
//   fast path (same-XCD group): publish = plain store (write-through L1 -> XCD L2);
//                               poll    = sc0 loads (L1-bypass, L2-hit, ~200-400 cy).
//   mirror (always written, agent scope, separate lines): proven LLC path; used by
//   mixed groups and as a sticky fallback if fast polling ever stalls (hang-proof).
__global__ __launch_bounds__(256, 1) void lstm_scan(
        const float* __restrict__ x,    // [B][T][256]
        const float* __restrict__ bx,   // [1024]
        const float* __restrict__ bh,   // [1024]
        const ushort_t* __restrict__ WxTh, const ushort_t* __restrict__ WxTl,
        const ushort_t* __restrict__ WhTh, const ushort_t* __restrict__ WhTl,
        float* __restrict__ out0,       // [B][T][256]
        float* __restrict__ outh,       // [B][256]
        float* __restrict__ outc,       // [B][256]
        uint_t* __restrict__ hbuf,      // fast lines: [2 par][4 grp][16 batch][256 col]
        uint_t* __restrict__ mbuf,      // mirror (agent scope), same layout
        uint_t* __restrict__ ctrl) {    // [0]=arrivals; [16..271]=placement table
    __shared__ ushort_t xah[16 * LDX], xal[16 * LDX];
    __shared__ ushort_t hsh[16 * LDX], hsl[16 * LDX];
    __shared__ float gatesL[1024];
    __shared__ float cst[256];
    __shared__ float bL[64];
    __shared__ int Lg, Ls, Lmode;

    const int tid = threadIdx.x;

    // ================= phase 0: publish placement, await all 256 blocks ============
    uint_t* table = ctrl + 16;
    if (tid == 0) {
        uint_t hwid = __builtin_amdgcn_s_getreg(63492);        // HW_REG_HW_ID (id 4), 32b
        uint_t xcc  = __builtin_amdgcn_s_getreg(63508) & 7u;   // HW_REG_XCC_ID (id 20)
        uint_t cuKey = (hwid >> 8) & 0xFFu;                    // CU/SH/SE bits
        __hip_atomic_store(&table[blockIdx.x], 1u | (xcc << 1) | (cuKey << 4),
                           __ATOMIC_RELAXED, __HIP_MEMORY_SCOPE_AGENT);
        __hip_atomic_fetch_add(&ctrl[0], 1u, __ATOMIC_RELEASE, __HIP_MEMORY_SCOPE_AGENT);
        while (__hip_atomic_load(&ctrl[0], __ATOMIC_ACQUIRE, __HIP_MEMORY_SCOPE_AGENT) < 256u)
            __builtin_amdgcn_s_sleep(2);
    }
    __syncthreads();
    // cooperative table fetch into LDS (reuse gatesL)
    uint_t* tabL = (uint_t*)gatesL;
    tabL[tid] = __hip_atomic_load(&table[tid], __ATOMIC_RELAXED, __HIP_MEMORY_SCOPE_AGENT);
    __syncthreads();

    // ============ phase 1: deterministic assignment (identical on every block) ======
    if (tid == 0) {
        int myg = -1, mys = -1, fmode = 0;
        int cntx[8]; for (int i = 0; i < 8; ++i) cntx[i] = 0;
        for (int b = 0; b < 256; ++b) cntx[(tabL[b] >> 1) & 7]++;
        int host[4]; unsigned usedx = 0;
        for (int g = 0; g < 4; ++g) {
            int best = -1;
            for (int xx = 0; xx < 8; ++xx)
                if (!((usedx >> xx) & 1) && (best < 0 || cntx[xx] > cntx[best])) best = xx;
            host[g] = best; usedx |= 1u << best;
        }
        unsigned taken[8]; for (int i = 0; i < 8; ++i) taken[i] = 0;
        for (int g = 0; g < 4; ++g) {
            int mem[16]; int n = 0; unsigned keys[16]; int allhost = 1;
            for (int b = 0; b < 256 && n < 16; ++b) {          // pass1: host xcd, distinct CU
                if ((taken[b >> 5] >> (b & 31)) & 1) continue;
                uint_t e = tabL[b]; if ((int)((e >> 1) & 7) != host[g]) continue;
                unsigned ck = (e >> 4) & 0xFFu; int dup = 0;
                for (int q = 0; q < n; ++q) if (keys[q] == ck) { dup = 1; break; }
                if (dup) continue;
                keys[n] = ck; mem[n++] = b; taken[b >> 5] |= 1u << (b & 31);
            }
            for (int b = 0; b < 256 && n < 16; ++b) {          // pass2: host xcd, any CU
                if ((taken[b >> 5] >> (b & 31)) & 1) continue;
                uint_t e = tabL[b]; if ((int)((e >> 1) & 7) != host[g]) continue;
                mem[n++] = b; taken[b >> 5] |= 1u << (b & 31);
            }
            for (int b = 0; b < 256 && n < 16; ++b) {          // pass3: anyone (mixed -> slow)
                if ((taken[b >> 5] >> (b & 31)) & 1) continue;
                mem[n++] = b; taken[b >> 5] |= 1u << (b & 31); allhost = 0;
            }
            for (int q = 0; q < 16; ++q)
                if (mem[q] == (int)blockIdx.x) { myg = g; mys = q; fmode = allhost; }
        }
        Lg = myg; Ls = mys; Lmode = fmode;
    }
    __syncthreads();
    if (Lg < 0) return;                    // surplus block: free the CU
    const int grp = Lg, s = Ls;
    const int fastmode = Lmode;
    __syncthreads();                       // everyone re-reads Lg; gatesL reusable after

    // ========================== phase 2: the scan ==================================
    const int lane = tid & 63, wave = tid >> 6;
    const int lm = lane & 15, lq = lane >> 4;
    const int pb = tid >> 4, pj = tid & 15;

    if (tid < 64) {
        int g = ((tid >> 4) << 8) + (s << 4) + (tid & 15);
        bL[tid] = bx[g] + bh[g];
    }
    cst[tid] = 0.0f;

    // loop-invariant B-fragments (our 16 gate cols of Wx and Wh, hi+lo) in registers
    const size_t wrow = ((size_t)((wave << 8) + (s << 4) + lm)) * 256;
    short8 fxh[8], fxl[8], fhh[8], fhl[8];
#pragma unroll
    for (int kc = 0; kc < 8; ++kc) {
        fxh[kc] = *(const short8*)(WxTh + wrow + kc * 32 + lq * 8);
        fxl[kc] = *(const short8*)(WxTl + wrow + kc * 32 + lq * 8);
        fhh[kc] = *(const short8*)(WhTh + wrow + kc * 32 + lq * 8);
        fhl[kc] = *(const short8*)(WhTl + wrow + kc * 32 + lq * 8);
    }

    const float* xp0 = x + ((size_t)(grp * 16 + pb)) * TT * 256 + pj * 16;
    float* o0 = out0 + ((size_t)(grp * 16 + pb)) * TT * H + (s << 4) + pj;

    float4_ xv[4];
#pragma unroll
    for (int q = 0; q < 4; ++q) xv[q] = *(const float4_*)(xp0 + q * 4);

    const int rb = pb * LDX + pj * 16;
    int fastpoll = fastmode;               // sticky: drops to 0 if fast lines ever stall

    for (int t = 0; t < TT; ++t) {
        // ---- stage prefetched x_t: split to hi/lo LDS ----
#pragma unroll
        for (int q = 0; q < 4; ++q) {
            union { ushort_t u[4]; ull q8; } ph_, pl_;
#pragma unroll
            for (int e = 0; e < 4; ++e) {
                ushort_t hi, lo; split2(xv[q][e], hi, lo);
                ph_.u[e] = hi; pl_.u[e] = lo;
            }
            *(ull*)(xah + rb + q * 4) = ph_.q8;
            *(ull*)(xal + rb + q * 4) = pl_.q8;
        }
        __syncthreads();   // S1: xa visible

        // ---- x @ Wx (independent of h; overlaps publish propagation) ----
        float4_ acc = {};
#pragma unroll
        for (int kc = 0; kc < 8; ++kc) {
            short8 ah = *(const short8*)(xah + lm * LDX + kc * 32 + lq * 8);
            short8 al = *(const short8*)(xal + lm * LDX + kc * 32 + lq * 8);
            acc = __builtin_amdgcn_mfma_f32_16x16x32_bf16(ah, fxh[kc], acc, 0, 0, 0);
            acc = __builtin_amdgcn_mfma_f32_16x16x32_bf16(ah, fxl[kc], acc, 0, 0, 0);
            acc = __builtin_amdgcn_mfma_f32_16x16x32_bf16(al, fxh[kc], acc, 0, 0, 0);
        }

        if (t > 0) {
            // ---- poll own 64B line (batch pb, cols pj*16..+15, writer block s'=pj) ----
            const size_t ridx = ((size_t)((((t & 1) << 2) + grp) << 12)) + (pb << 8) + (pj << 4);
            const uint_t* hp = hbuf + ridx;
            const uint_t* mp = mbuf + ridx;
            const uint_t texp = (uint_t)(t & 127);
            uint_t w[16];
            int got = 0;
            if (fastpoll) {
                int rounds = 0;
                while (true) {
                    uint4_ a0, a1, a2, a3;
                    asm volatile(
                        "global_load_dwordx4 %0, %4, off sc0\n\t"
                        "global_load_dwordx4 %1, %4, off offset:16 sc0\n\t"
                        "global_load_dwordx4 %2, %4, off offset:32 sc0\n\t"
                        "global_load_dwordx4 %3, %4, off offset:48 sc0\n\t"
                        "s_waitcnt vmcnt(0)"
                        : "=&v"(a0), "=&v"(a1), "=&v"(a2), "=&v"(a3)
                        : "v"(hp) : "memory");
                    bool ok = true;
#pragma unroll
                    for (int e = 0; e < 4; ++e) {
                        ok &= ((a0[e] & 127u) == texp); ok &= ((a1[e] & 127u) == texp);
                        ok &= ((a2[e] & 127u) == texp); ok &= ((a3[e] & 127u) == texp);
                    }
                    if (ok) {
#pragma unroll
                        for (int e = 0; e < 4; ++e) {
                            w[e] = a0[e]; w[4 + e] = a1[e]; w[8 + e] = a2[e]; w[12 + e] = a3[e];
                        }
                        got = 1; break;
                    }
                    if (++rounds > 1024) { fastpoll = 0; break; }   // sticky fallback
                }
            }
            if (!got) {
                while (true) {
                    bool ok = true;
#pragma unroll
                    for (int e = 0; e < 16; ++e)
                        w[e] = __hip_atomic_load(mp + e, __ATOMIC_RELAXED, __HIP_MEMORY_SCOPE_AGENT);
#pragma unroll
                    for (int e = 0; e < 16; ++e) ok &= ((w[e] & 127u) == texp);
                    if (ok) break;
                }
            }
            // ---- split (deterministic, identical on all blocks) and stage into LDS ----
#pragma unroll
            for (int q = 0; q < 4; ++q) {
                union { ushort_t u[4]; ull q8; } ph_, pl_;
#pragma unroll
                for (int e = 0; e < 4; ++e) {
                    float v = __uint_as_float(w[q * 4 + e] & ~127u);
                    ushort_t hi, lo; split2(v, hi, lo);
                    ph_.u[e] = hi; pl_.u[e] = lo;
                }
                *(ull*)(hsh + rb + q * 4) = ph_.q8;
                *(ull*)(hsl + rb + q * 4) = pl_.q8;
            }
            __syncthreads();   // S2: h planes visible

            // ---- prefetch x_{t+1} here: long gap to use, and poll's vmcnt(0) no longer
            //      drains an in-flight HBM load every step ----
            if (t + 1 < TT) {
                const float* xp = xp0 + (size_t)(t + 1) * 256;
#pragma unroll
                for (int q = 0; q < 4; ++q) xv[q] = *(const float4_*)(xp + q * 4);
            }

            // ---- h @ Wh ----
#pragma unroll
            for (int kc = 0; kc < 8; ++kc) {
                short8 ah = *(const short8*)(hsh + lm * LDX + kc * 32 + lq * 8);
                short8 al = *(const short8*)(hsl + lm * LDX + kc * 32 + lq * 8);
                acc = __builtin_amdgcn_mfma_f32_16x16x32_bf16(ah, fhh[kc], acc, 0, 0, 0);
                acc = __builtin_amdgcn_mfma_f32_16x16x32_bf16(ah, fhl[kc], acc, 0, 0, 0);
                acc = __builtin_amdgcn_mfma_f32_16x16x32_bf16(al, fhh[kc], acc, 0, 0, 0);
            }
        } else {
            const float* xp = xp0 + (size_t)256;
#pragma unroll
            for (int q = 0; q < 4; ++q) xv[q] = *(const float4_*)(xp + q * 4);
        }

        // C layout: col = lane&15 (=j), row = (lane>>4)*4+r (=batch)
#pragma unroll
        for (int r = 0; r < 4; ++r)
            gatesL[(wave << 8) + ((lq * 4 + r) << 4) + lm] = acc[r];
        __syncthreads();   // S3: gates ready

        // ---- pointwise cell: thread = (batch pb, col pj) ----
        float g0 = gatesL[tid]       + bL[pj];        // f
        float g1 = gatesL[256 + tid] + bL[16 + pj];   // i
        float g2 = gatesL[512 + tid] + bL[32 + pj];   // o
        float g3 = gatesL[768 + tid] + bL[48 + pj];   // chat
        float ft = sigm(g0), it = sigm(g1), ot = sigm(g2), ch = tanh_(g3);
        float c = ft * cst[tid] + it * ch;
        cst[tid] = c;
        float hv = ot * tanh_(c);

        // mask low 7 mantissa bits (tag space); recurrence AND output use the masked value
        uint_t um = __float_as_uint(hv) & ~127u;
        float hm = __uint_as_float(um);
        o0[(size_t)t * H] = hm;

        // ---- publish tagged word ----
        const uint_t tagged = um | (uint_t)((t + 1) & 127);
        const size_t widx = ((size_t)(((((t & 1) ^ 1) << 2) + grp) << 12)) + (pb << 8) + (s << 4) + pj;
        if (fastmode)
            __hip_atomic_store(hbuf + widx, tagged, __ATOMIC_RELAXED, __HIP_MEMORY_SCOPE_WORKGROUP);
        __hip_atomic_store(mbuf + widx, tagged, __ATOMIC_RELAXED, __HIP_MEMORY_SCOPE_AGENT);

        if (t == TT - 1) {
            outh[(grp * 16 + pb) * H + (s << 4) + pj] = hm;
            outc[(grp * 16 + pb) * H + (s << 4) + pj] = c;
        }
        // no trailing barrier: tag protocol is self-validating per 4B word
    }
}

extern "C" void kernel_launch(void* const* d_in, const int* in_sizes, int n_in,
                              void* d_out, int out_size, void* d_ws, size_t ws_size,
                              hipStream_t stream) {
    (void)in_sizes; (void)n_in; (void)out_size; (void)ws_size;
    const float* x  = (const float*)d_in[0];
    const float* Wx = (const float*)d_in[1];
    const float* Wh = (const float*)d_in[2];
    const float* bx = (const float*)d_in[3];
    const float* bh = (const float*)d_in[4];
    float* out0 = (float*)d_out;
    float* outh = out0 + (size_t)BB * TT * H;
    float* outc = outh + (size_t)BB * H;

    // ws: hbuf 128K | mbuf 128K | ctrl+table 2K | W planes 2 MB
    uint_t* hbuf = (uint_t*)d_ws;
    uint_t* mbuf = (uint_t*)((char*)d_ws + 131072);
    uint_t* ctrl = (uint_t*)((char*)d_ws + 262144);
    ushort_t* planes = (ushort_t*)((char*)d_ws + 264192);

    hipMemsetAsync(d_ws, 0, 264192, stream);
    split_w<<<2048, 256, 0, stream>>>(Wx, Wh, planes);
    lstm_scan<<<256, 256, 0, stream>>>(x, bx, bh,
        planes,
        planes + (size_t)G4 * 256,
        planes + (size_t)2 * G4 * 256,
        planes + (size_t)3 * G4 * 256,
        out0, outh, outc, hbuf, mbuf, ctrl);
}

// Round 3
// 8499.395 us; speedup vs baseline: 1.7592x; 1.7592x over previous
//
#include <hip/hip_runtime.h>
#include <stdint.h>

#define H 256
#define BB 64
#define TT 2048
#define G4 1024

typedef __attribute__((ext_vector_type(8))) short short8;
typedef __attribute__((ext_vector_type(4))) float float4_;
typedef unsigned long long ull;
typedef unsigned short ushort_t;
typedef unsigned int uint_t;

static __device__ __forceinline__ float bfhi2f(ushort_t u) {
    union { unsigned int i; float f; } v; v.i = ((unsigned int)u) << 16; return v.f;
}
static __device__ __forceinline__ ushort_t f2bf(float x) {
    union { float f; unsigned int i; } v; v.f = x;
    unsigned int u = v.i;
    return (ushort_t)((u + 0x7FFFu + ((u >> 16) & 1u)) >> 16);
}
static __device__ __forceinline__ void split2(float x, ushort_t& hi, ushort_t& lo) {
    hi = f2bf(x);
    lo = f2bf(x - bfhi2f(hi));
}
static __device__ __forceinline__ float sigm(float x) { return 1.0f / (1.0f + __expf(-x)); }
static __device__ __forceinline__ float tanh_(float x) { return 2.0f / (1.0f + __expf(-2.0f * x)) - 1.0f; }

// ---- split fp32 weights into transposed bf16 hi/lo planes: planes[mat][plane][g][k] ----
__global__ __launch_bounds__(256) void split_w(const float* __restrict__ Wx,
                                               const float* __restrict__ Wh,
                                               ushort_t* __restrict__ planes) {
    const int g = blockIdx.x & 1023;
    const int mat = blockIdx.x >> 10;
    const int k = threadIdx.x;
    const float* src = mat ? Wh : Wx;
    float v = src[(size_t)k * G4 + g];
    ushort_t hi, lo; split2(v, hi, lo);
    ushort_t* ph = planes + (size_t)mat * 2 * G4 * 256;
    ph[g * 256 + k] = hi;
    ph[(size_t)G4 * 256 + g * 256 + k] = lo;
}

// ---- fused LSTM scan, split-bf16 (fp32-grade) arithmetic ----
// 64 blocks: grp = blockIdx.x & 3 (16-batch group), s = blockIdx.x >> 2 (16-wide j-slice).
// Wave w = gate type w (f,i,o,chat). Loop-invariant W fragments live in registers.
// h exchange: round-1 tagged-word protocol over agent scope (proven).
//
// NEW this round: LDS bank-conflict elimination.
//  * x/h hi/lo tiles: natural [16][256] layout (512 B rows) + XOR swizzle
//    byte ^= ((row&7)<<4) applied on BOTH the stage-write side (row=pb) and the
//    MFMA fragment-read side (row=lm). This is the guide-verified fix for the
//    "row-major tile, ds_read_b128 across rows at same col-range" conflict.
//  * gatesL: col ^= row swizzle -> MFMA-result scatter writes (previously 4-way
//    conflicted: banks depended only on (row&1, lm)) and pointwise gathers both
//    become conflict-free.
__global__ __launch_bounds__(256, 1) void lstm_scan(
        const float* __restrict__ x,    // [B][T][256]
        const float* __restrict__ bx,   // [1024]
        const float* __restrict__ bh,   // [1024]
        const ushort_t* __restrict__ WxTh, const ushort_t* __restrict__ WxTl,
        const ushort_t* __restrict__ WhTh, const ushort_t* __restrict__ WhTl,
        float* __restrict__ out0,       // [B][T][256]
        float* __restrict__ outh,       // [B][256]
        float* __restrict__ outc,       // [B][256]
        uint_t* __restrict__ hbuf) {    // [2 par][4 grp][16 batch][256 col] fp32+tag
    __shared__ ushort_t xah[16 * 256], xal[16 * 256];   // 8 KB each, 512 B rows
    __shared__ ushort_t hsh[16 * 256], hsl[16 * 256];
    __shared__ float gatesL[1024];
    __shared__ float cst[256];
    __shared__ float bL[64];

    const int tid = threadIdx.x;
    const int grp = blockIdx.x & 3;
    const int s = blockIdx.x >> 2;
    const int lane = tid & 63, wave = tid >> 6;
    const int lm = lane & 15, lq = lane >> 4;
    const int pb = tid >> 4, pj = tid & 15;

    char* xahB = (char*)xah; char* xalB = (char*)xal;
    char* hshB = (char*)hsh; char* hslB = (char*)hsl;
    const int swst = (pb & 7) << 4;     // stage-write swizzle (row = pb)
    const int swrd = (lm & 7) << 4;     // fragment-read swizzle (row = lm)
    const int stbase = (pb << 9) + (pj << 5);   // byte base of this thread's 16 elems

    if (tid < 64) {
        int g = ((tid >> 4) << 8) + (s << 4) + (tid & 15);
        bL[tid] = bx[g] + bh[g];
    }
    cst[tid] = 0.0f;

    // loop-invariant B-fragments (our 16 gate cols of Wx and Wh, hi+lo) in registers
    const size_t wrow = ((size_t)((wave << 8) + (s << 4) + lm)) * 256;
    short8 fxh[8], fxl[8], fhh[8], fhl[8];
#pragma unroll
    for (int kc = 0; kc < 8; ++kc) {
        fxh[kc] = *(const short8*)(WxTh + wrow + kc * 32 + lq * 8);
        fxl[kc] = *(const short8*)(WxTl + wrow + kc * 32 + lq * 8);
        fhh[kc] = *(const short8*)(WhTh + wrow + kc * 32 + lq * 8);
        fhl[kc] = *(const short8*)(WhTl + wrow + kc * 32 + lq * 8);
    }

    const float* xp0 = x + ((size_t)(grp * 16 + pb)) * TT * 256 + pj * 16;
    float* o0 = out0 + ((size_t)(grp * 16 + pb)) * TT * H + (s << 4) + pj;

    // prefetch x_0 into registers
    float4_ xv[4];
#pragma unroll
    for (int q = 0; q < 4; ++q) xv[q] = *(const float4_*)(xp0 + q * 4);

    for (int t = 0; t < TT; ++t) {
        // ---- stage prefetched x_t: split to hi/lo LDS (swizzled) ----
#pragma unroll
        for (int q = 0; q < 4; ++q) {
            union { ushort_t u[4]; ull q8; } ph_, pl_;
#pragma unroll
            for (int e = 0; e < 4; ++e) {
                ushort_t hi, lo; split2(xv[q][e], hi, lo);
                ph_.u[e] = hi; pl_.u[e] = lo;
            }
            *(ull*)(xahB + ((stbase + (q << 3)) ^ swst)) = ph_.q8;
            *(ull*)(xalB + ((stbase + (q << 3)) ^ swst)) = pl_.q8;
        }
        __syncthreads();   // S1: xa visible

        // ---- issue first h poll-load batch (thread (pb,pj) owns batch pb, cols pj*16..+15,
        //      all 16 words written by writer block s'=pj) ----
        const uint_t* hp = hbuf + ((((t & 1) << 2) + grp) << 12) + (pb << 8) + (pj << 4);
        uint_t w[16];
        if (t > 0) {
#pragma unroll
            for (int e = 0; e < 16; ++e)
                w[e] = __hip_atomic_load(hp + e, __ATOMIC_RELAXED, __HIP_MEMORY_SCOPE_AGENT);
        }

        // ---- x @ Wx (independent of h; overlaps publish-propagation + poll latency) ----
        float4_ acc = {};
#pragma unroll
        for (int kc = 0; kc < 8; ++kc) {
            short8 ah = *(const short8*)(xahB + (((lm << 9) + (kc << 6) + (lq << 4)) ^ swrd));
            short8 al = *(const short8*)(xalB + (((lm << 9) + (kc << 6) + (lq << 4)) ^ swrd));
            acc = __builtin_amdgcn_mfma_f32_16x16x32_bf16(ah, fxh[kc], acc, 0, 0, 0);
            acc = __builtin_amdgcn_mfma_f32_16x16x32_bf16(ah, fxl[kc], acc, 0, 0, 0);
            acc = __builtin_amdgcn_mfma_f32_16x16x32_bf16(al, fxh[kc], acc, 0, 0, 0);
        }

        // ---- prefetch x_{t+1} (in flight during the poll window) ----
        if (t + 1 < TT) {
            const float* xp = xp0 + (size_t)(t + 1) * 256;
#pragma unroll
            for (int q = 0; q < 4; ++q) xv[q] = *(const float4_*)(xp + q * 4);
        }

        if (t > 0) {
            // ---- poll own words until all tags match; the successful load IS the data ----
            const uint_t texp = (uint_t)(t & 127);
            while (true) {
                bool ok = true;
#pragma unroll
                for (int e = 0; e < 16; ++e) ok &= ((w[e] & 127u) == texp);
                if (ok) break;
#pragma unroll
                for (int e = 0; e < 16; ++e)
                    w[e] = __hip_atomic_load(hp + e, __ATOMIC_RELAXED, __HIP_MEMORY_SCOPE_AGENT);
            }
            // ---- split (deterministic, identical on all blocks) and stage into LDS ----
#pragma unroll
            for (int q = 0; q < 4; ++q) {
                union { ushort_t u[4]; ull q8; } ph_, pl_;
#pragma unroll
                for (int e = 0; e < 4; ++e) {
                    float v = __uint_as_float(w[q * 4 + e] & ~127u);
                    ushort_t hi, lo; split2(v, hi, lo);
                    ph_.u[e] = hi; pl_.u[e] = lo;
                }
                *(ull*)(hshB + ((stbase + (q << 3)) ^ swst)) = ph_.q8;
                *(ull*)(hslB + ((stbase + (q << 3)) ^ swst)) = pl_.q8;
            }
            __syncthreads();   // S2: h planes visible

            // ---- h @ Wh ----
#pragma unroll
            for (int kc = 0; kc < 8; ++kc) {
                short8 ah = *(const short8*)(hshB + (((lm << 9) + (kc << 6) + (lq << 4)) ^ swrd));
                short8 al = *(const short8*)(hslB + (((lm << 9) + (kc << 6) + (lq << 4)) ^ swrd));
                acc = __builtin_amdgcn_mfma_f32_16x16x32_bf16(ah, fhh[kc], acc, 0, 0, 0);
                acc = __builtin_amdgcn_mfma_f32_16x16x32_bf16(ah, fhl[kc], acc, 0, 0, 0);
                acc = __builtin_amdgcn_mfma_f32_16x16x32_bf16(al, fhh[kc], acc, 0, 0, 0);
            }
        }

        // C layout: col = lane&15 (=j), row = (lane>>4)*4+r (=batch); col^row swizzle
#pragma unroll
        for (int r = 0; r < 4; ++r) {
            const int row = lq * 4 + r;
            gatesL[(wave << 8) + (row << 4) + (lm ^ row)] = acc[r];
        }
        __syncthreads();   // S3: gates ready

        // ---- pointwise cell: thread = (batch pb, col pj); read with same swizzle ----
        const int gidx = (pb << 4) + (pj ^ pb);
        float g0 = gatesL[gidx]       + bL[pj];        // f
        float g1 = gatesL[256 + gidx] + bL[16 + pj];   // i
        float g2 = gatesL[512 + gidx] + bL[32 + pj];   // o
        float g3 = gatesL[768 + gidx] + bL[48 + pj];   // chat
        float ft = sigm(g0), it = sigm(g1), ot = sigm(g2), ch = tanh_(g3);
        float c = ft * cst[tid] + it * ch;
        cst[tid] = c;
        float hv = ot * tanh_(c);

        // mask low 7 mantissa bits (tag space); recurrence AND output use the masked value
        uint_t um = __float_as_uint(hv) & ~127u;
        float hm = __uint_as_float(um);
        o0[(size_t)t * H] = hm;

        // ---- publish tagged word (fire-and-forget; drains in next step's shadow) ----
        uint_t* hw = hbuf + (((((t & 1) ^ 1) << 2) + grp) << 12) + (pb << 8) + (s << 4) + pj;
        __hip_atomic_store(hw, um | (uint_t)((t + 1) & 127), __ATOMIC_RELAXED, __HIP_MEMORY_SCOPE_AGENT);

        if (t == TT - 1) {
            outh[(grp * 16 + pb) * H + (s << 4) + pj] = hm;
            outc[(grp * 16 + pb) * H + (s << 4) + pj] = c;
        }
        // no trailing barrier: tag protocol is self-validating per 4B word
    }
}

extern "C" void kernel_launch(void* const* d_in, const int* in_sizes, int n_in,
                              void* d_out, int out_size, void* d_ws, size_t ws_size,
                              hipStream_t stream) {
    (void)in_sizes; (void)n_in; (void)out_size; (void)ws_size;
    const float* x  = (const float*)d_in[0];
    const float* Wx = (const float*)d_in[1];
    const float* Wh = (const float*)d_in[2];
    const float* bx = (const float*)d_in[3];
    const float* bh = (const float*)d_in[4];
    float* out0 = (float*)d_out;
    float* outh = out0 + (size_t)BB * TT * H;
    float* outc = outh + (size_t)BB * H;

    // ws layout: hbuf [2][4][16][256] fp32 = 131072 B | pad 128 | W planes 2 MB
    uint_t* hbuf = (uint_t*)d_ws;
    ushort_t* planes = (ushort_t*)((char*)d_ws + 131072 + 128);

    hipMemsetAsync(d_ws, 0, 131072 + 128, stream);
    split_w<<<2048, 256, 0, stream>>>(Wx, Wh, planes);
    lstm_scan<<<64, 256, 0, stream>>>(x, bx, bh,
        planes,
        planes + (size_t)G4 * 256,
        planes + (size_t)2 * G4 * 256,
        planes + (size_t)3 * G4 * 256,
        out0, outh, outc, hbuf);
}

// Round 4
// 7887.921 us; speedup vs baseline: 1.8956x; 1.0775x over previous
//
#include <hip/hip_runtime.h>
#include <stdint.h>

#define H 256
#define BB 64
#define TT 2048
#define G4 1024
#define LDX 264   // padded LDS row stride (elems): 528 B, 16B-aligned, balanced banks

typedef __attribute__((ext_vector_type(8))) short short8;
typedef __attribute__((ext_vector_type(4))) float float4_;
typedef unsigned long long ull;
typedef unsigned short ushort_t;
typedef unsigned int uint_t;

static __device__ __forceinline__ float bfhi2f(ushort_t u) {
    union { unsigned int i; float f; } v; v.i = ((unsigned int)u) << 16; return v.f;
}
static __device__ __forceinline__ ushort_t f2bf(float x) {
    union { float f; unsigned int i; } v; v.f = x;
    unsigned int u = v.i;
    return (ushort_t)((u + 0x7FFFu + ((u >> 16) & 1u)) >> 16);
}
static __device__ __forceinline__ void split2(float x, ushort_t& hi, ushort_t& lo) {
    hi = f2bf(x);
    lo = f2bf(x - bfhi2f(hi));
}
static __device__ __forceinline__ float sigm(float x) { return 1.0f / (1.0f + __expf(-x)); }
static __device__ __forceinline__ float tanh_(float x) { return 2.0f / (1.0f + __expf(-2.0f * x)) - 1.0f; }

// ---- split fp32 weights into transposed bf16 hi/lo planes: planes[mat][plane][g][k] ----
__global__ __launch_bounds__(256) void split_w(const float* __restrict__ Wx,
                                               const float* __restrict__ Wh,
                                               ushort_t* __restrict__ planes) {
    const int g = blockIdx.x & 1023;
    const int mat = blockIdx.x >> 10;
    const int k = threadIdx.x;
    const float* src = mat ? Wh : Wx;
    float v = src[(size_t)k * G4 + g];
    ushort_t hi, lo; split2(v, hi, lo);
    ushort_t* ph = planes + (size_t)mat * 2 * G4 * 256;
    ph[g * 256 + k] = hi;
    ph[(size_t)G4 * 256 + g * 256 + k] = lo;
}

// ---- fused LSTM scan, split-bf16 (fp32-grade) arithmetic ----
// blocks 0..63: workers (round-1 proven core, LDX=264 layout, tagged-word exchange).
// blocks 64..255: BALLAST — spin independent VALU FMAs to keep chip-wide issue
// activity high so the SCLK governor does not park the chip at a low DPM state
// (hypothesis: the stable 9.8k "cycles"/step is really ~4k cycles at ~1 GHz).
// Ballast exits when ctrl[0] reaches 64 (each worker block increments at the end),
// with a hard iteration cap as a safety net.
__global__ __launch_bounds__(256, 1) void lstm_scan(
        const float* __restrict__ x,    // [B][T][256]
        const float* __restrict__ bx,   // [1024]
        const float* __restrict__ bh,   // [1024]
        const ushort_t* __restrict__ WxTh, const ushort_t* __restrict__ WxTl,
        const ushort_t* __restrict__ WhTh, const ushort_t* __restrict__ WhTl,
        float* __restrict__ out0,       // [B][T][256]
        float* __restrict__ outh,       // [B][256]
        float* __restrict__ outc,       // [B][256]
        uint_t* __restrict__ hbuf,      // [2 par][4 grp][16 batch][256 col] fp32+tag
        uint_t* __restrict__ ctrl) {    // [0] = worker-done counter
    __shared__ ushort_t xah[16 * LDX], xal[16 * LDX];
    __shared__ ushort_t hsh[16 * LDX], hsl[16 * LDX];
    __shared__ float gatesL[1024];
    __shared__ float cst[256];
    __shared__ float bL[64];

    const int tid = threadIdx.x;

    if (blockIdx.x >= 64) {
        // ================= ballast: keep the clock governor awake =================
        float a0 = 1.0f + tid * 1e-7f, a1 = 1.1f, a2 = 1.2f, a3 = 1.3f;
        const float b = 1.0000001f, c = 1e-9f;
        for (int it = 0; it < 40000; ++it) {
#pragma unroll 32
            for (int k = 0; k < 256; ++k) {
                a0 = __builtin_fmaf(a0, b, c);
                a1 = __builtin_fmaf(a1, b, c);
                a2 = __builtin_fmaf(a2, b, c);
                a3 = __builtin_fmaf(a3, b, c);
            }
            if (__hip_atomic_load(&ctrl[0], __ATOMIC_RELAXED, __HIP_MEMORY_SCOPE_AGENT) >= 64u)
                break;
        }
        asm volatile("" :: "v"(a0), "v"(a1), "v"(a2), "v"(a3));   // keep live (no DCE)
        return;
    }

    // ============================ worker (round-1 core) ===========================
    const int grp = blockIdx.x & 3;
    const int s = blockIdx.x >> 2;
    const int lane = tid & 63, wave = tid >> 6;
    const int lm = lane & 15, lq = lane >> 4;
    const int pb = tid >> 4, pj = tid & 15;

    if (tid < 64) {
        int g = ((tid >> 4) << 8) + (s << 4) + (tid & 15);
        bL[tid] = bx[g] + bh[g];
    }
    cst[tid] = 0.0f;

    // loop-invariant B-fragments (our 16 gate cols of Wx and Wh, hi+lo) in registers
    const size_t wrow = ((size_t)((wave << 8) + (s << 4) + lm)) * 256;
    short8 fxh[8], fxl[8], fhh[8], fhl[8];
#pragma unroll
    for (int kc = 0; kc < 8; ++kc) {
        fxh[kc] = *(const short8*)(WxTh + wrow + kc * 32 + lq * 8);
        fxl[kc] = *(const short8*)(WxTl + wrow + kc * 32 + lq * 8);
        fhh[kc] = *(const short8*)(WhTh + wrow + kc * 32 + lq * 8);
        fhl[kc] = *(const short8*)(WhTl + wrow + kc * 32 + lq * 8);
    }

    const float* xp0 = x + ((size_t)(grp * 16 + pb)) * TT * 256 + pj * 16;
    float* o0 = out0 + ((size_t)(grp * 16 + pb)) * TT * H + (s << 4) + pj;

    // prefetch x_0 into registers
    float4_ xv[4];
#pragma unroll
    for (int q = 0; q < 4; ++q) xv[q] = *(const float4_*)(xp0 + q * 4);

    const int rb = pb * LDX + pj * 16;

    for (int t = 0; t < TT; ++t) {
        // ---- stage prefetched x_t: split to hi/lo LDS ----
#pragma unroll
        for (int q = 0; q < 4; ++q) {
            union { ushort_t u[4]; ull q8; } ph_, pl_;
#pragma unroll
            for (int e = 0; e < 4; ++e) {
                ushort_t hi, lo; split2(xv[q][e], hi, lo);
                ph_.u[e] = hi; pl_.u[e] = lo;
            }
            *(ull*)(xah + rb + q * 4) = ph_.q8;
            *(ull*)(xal + rb + q * 4) = pl_.q8;
        }
        __syncthreads();   // S1: xa visible

        // ---- issue first h poll-load batch (thread (pb,pj) owns batch pb, cols pj*16..+15,
        //      all 16 words written by writer block s'=pj) ----
        const uint_t* hp = hbuf + ((((t & 1) << 2) + grp) << 12) + (pb << 8) + (pj << 4);
        uint_t w[16];
        if (t > 0) {
#pragma unroll
            for (int e = 0; e < 16; ++e)
                w[e] = __hip_atomic_load(hp + e, __ATOMIC_RELAXED, __HIP_MEMORY_SCOPE_AGENT);
        }

        // ---- x @ Wx (independent of h; overlaps publish-propagation + poll latency) ----
        float4_ acc = {};
#pragma unroll
        for (int kc = 0; kc < 8; ++kc) {
            short8 ah = *(const short8*)(xah + lm * LDX + kc * 32 + lq * 8);
            short8 al = *(const short8*)(xal + lm * LDX + kc * 32 + lq * 8);
            acc = __builtin_amdgcn_mfma_f32_16x16x32_bf16(ah, fxh[kc], acc, 0, 0, 0);
            acc = __builtin_amdgcn_mfma_f32_16x16x32_bf16(ah, fxl[kc], acc, 0, 0, 0);
            acc = __builtin_amdgcn_mfma_f32_16x16x32_bf16(al, fxh[kc], acc, 0, 0, 0);
        }

        if (t > 0) {
            // ---- poll own words until all tags match; the successful load IS the data ----
            const uint_t texp = (uint_t)(t & 127);
            while (true) {
                bool ok = true;
#pragma unroll
                for (int e = 0; e < 16; ++e) ok &= ((w[e] & 127u) == texp);
                if (ok) break;
#pragma unroll
                for (int e = 0; e < 16; ++e)
                    w[e] = __hip_atomic_load(hp + e, __ATOMIC_RELAXED, __HIP_MEMORY_SCOPE_AGENT);
            }
        }

        // ---- prefetch x_{t+1} AFTER the poll: its HBM latency now hides under the
        //      h-stage + S2 + h-MFMA stretch instead of being drained by the poll's
        //      vmcnt(0) on the critical path ----
        if (t + 1 < TT) {
            const float* xp = xp0 + (size_t)(t + 1) * 256;
#pragma unroll
            for (int q = 0; q < 4; ++q) xv[q] = *(const float4_*)(xp + q * 4);
        }

        if (t > 0) {
            // ---- split (deterministic, identical on all blocks) and stage into LDS ----
#pragma unroll
            for (int q = 0; q < 4; ++q) {
                union { ushort_t u[4]; ull q8; } ph_, pl_;
#pragma unroll
                for (int e = 0; e < 4; ++e) {
                    float v = __uint_as_float(w[q * 4 + e] & ~127u);
                    ushort_t hi, lo; split2(v, hi, lo);
                    ph_.u[e] = hi; pl_.u[e] = lo;
                }
                *(ull*)(hsh + rb + q * 4) = ph_.q8;
                *(ull*)(hsl + rb + q * 4) = pl_.q8;
            }
            __syncthreads();   // S2: h planes visible

            // ---- h @ Wh ----
#pragma unroll
            for (int kc = 0; kc < 8; ++kc) {
                short8 ah = *(const short8*)(hsh + lm * LDX + kc * 32 + lq * 8);
                short8 al = *(const short8*)(hsl + lm * LDX + kc * 32 + lq * 8);
                acc = __builtin_amdgcn_mfma_f32_16x16x32_bf16(ah, fhh[kc], acc, 0, 0, 0);
                acc = __builtin_amdgcn_mfma_f32_16x16x32_bf16(ah, fhl[kc], acc, 0, 0, 0);
                acc = __builtin_amdgcn_mfma_f32_16x16x32_bf16(al, fhh[kc], acc, 0, 0, 0);
            }
        }

        // C layout: col = lane&15 (=j), row = (lane>>4)*4+r (=batch)
#pragma unroll
        for (int r = 0; r < 4; ++r)
            gatesL[(wave << 8) + ((lq * 4 + r) << 4) + lm] = acc[r];
        __syncthreads();   // S3: gates ready

        // ---- pointwise cell: thread = (batch pb, col pj) ----
        float g0 = gatesL[tid]       + bL[pj];        // f
        float g1 = gatesL[256 + tid] + bL[16 + pj];   // i
        float g2 = gatesL[512 + tid] + bL[32 + pj];   // o
        float g3 = gatesL[768 + tid] + bL[48 + pj];   // chat
        float ft = sigm(g0), it = sigm(g1), ot = sigm(g2), ch = tanh_(g3);
        float c = ft * cst[tid] + it * ch;
        cst[tid] = c;
        float hv = ot * tanh_(c);

        // mask low 7 mantissa bits (tag space); recurrence AND output use the masked value
        uint_t um = __float_as_uint(hv) & ~127u;
        float hm = __uint_as_float(um);
        o0[(size_t)t * H] = hm;

        // ---- publish tagged word (fire-and-forget; drains in next step's shadow) ----
        uint_t* hw = hbuf + (((((t & 1) ^ 1) << 2) + grp) << 12) + (pb << 8) + (s << 4) + pj;
        __hip_atomic_store(hw, um | (uint_t)((t + 1) & 127), __ATOMIC_RELAXED, __HIP_MEMORY_SCOPE_AGENT);

        if (t == TT - 1) {
            outh[(grp * 16 + pb) * H + (s << 4) + pj] = hm;
            outc[(grp * 16 + pb) * H + (s << 4) + pj] = c;
        }
        // no trailing barrier: tag protocol is self-validating per 4B word
    }

    // signal ballast that this worker block is done
    if (tid == 0)
        __hip_atomic_fetch_add(&ctrl[0], 1u, __ATOMIC_RELEASE, __HIP_MEMORY_SCOPE_AGENT);
}

extern "C" void kernel_launch(void* const* d_in, const int* in_sizes, int n_in,
                              void* d_out, int out_size, void* d_ws, size_t ws_size,
                              hipStream_t stream) {
    (void)in_sizes; (void)n_in; (void)out_size; (void)ws_size;
    const float* x  = (const float*)d_in[0];
    const float* Wx = (const float*)d_in[1];
    const float* Wh = (const float*)d_in[2];
    const float* bx = (const float*)d_in[3];
    const float* bh = (const float*)d_in[4];
    float* out0 = (float*)d_out;
    float* outh = out0 + (size_t)BB * TT * H;
    float* outc = outh + (size_t)BB * H;

    // ws layout: hbuf [2][4][16][256] fp32 = 131072 B | ctrl 128 B | W planes 2 MB
    uint_t* hbuf = (uint_t*)d_ws;
    uint_t* ctrl = (uint_t*)((char*)d_ws + 131072);
    ushort_t* planes = (ushort_t*)((char*)d_ws + 131072 + 128);

    hipMemsetAsync(d_ws, 0, 131072 + 128, stream);
    split_w<<<2048, 256, 0, stream>>>(Wx, Wh, planes);
    lstm_scan<<<256, 256, 0, stream>>>(x, bx, bh,
        planes,
        planes + (size_t)G4 * 256,
        planes + (size_t)2 * G4 * 256,
        planes + (size_t)3 * G4 * 256,
        out0, outh, outc, hbuf, ctrl);
}